// Round 7
// baseline (86.334 us; speedup 1.0000x reference)
//
#include <hip/hip_runtime.h>
#include <stdint.h>

#define NN 4096
#define DD 256
#define TH 0.04f

typedef __attribute__((ext_vector_type(4))) float f32x4;
typedef __attribute__((ext_vector_type(16))) float f32x16;
typedef __attribute__((ext_vector_type(8))) short s16x8;
typedef unsigned short us;

__device__ __forceinline__ us f2bf(float f) {
  union { float f; uint32_t u; } x; x.f = f;
  uint32_t u = x.u;
  return (us)((u + 0x7FFFu + ((u >> 16) & 1u)) >> 16);  // RNE
}
__device__ __forceinline__ float bf2f(us h) {
  union { uint32_t u; float f; } x; x.u = ((uint32_t)h) << 16;
  return x.f;
}

// ======== hw block: P = H@W (bf16 MFMA, fp32 H/W inputs, W staged via LDS).
// 16 u-rows per block, 256 threads. Emits P self [u][d] bf16 + 32x32x16
// B-fragment panels hWbP[dt(8)][sg(256)][512].
__device__ __forceinline__ void hw_block(const float* __restrict__ H,
                                         const float* __restrict__ W,
                                         int u0,
                                         us* __restrict__ hWb,
                                         us* __restrict__ hWbP,
                                         char* smem) {
  us (*hs)[264] = reinterpret_cast<us(*)[264]>(smem);                    // 8448 B
  us (*wt)[34]  = reinterpret_cast<us(*)[34]>(smem + 16 * 264 * 2);      // 17408 B
  us (*lt)[260] = reinterpret_cast<us(*)[260]>(smem + 16 * 264 * 2 + 256 * 34 * 2); // 8320 B
  const int t = threadIdx.x;
  // stage H tile 16x256 -> bf16 (coalesced)
#pragma unroll
  for (int rep = 0; rep < 4; ++rep) {
    const int flat = rep * 256 + t;
    const int row = flat >> 6, c4 = (flat & 63) * 4;
    f32x4 v = *reinterpret_cast<const f32x4*>(H + (size_t)(u0 + row) * DD + c4);
    uint2 pw;
    pw.x = (uint32_t)f2bf(v[0]) | ((uint32_t)f2bf(v[1]) << 16);
    pw.y = (uint32_t)f2bf(v[2]) | ((uint32_t)f2bf(v[3]) << 16);
    *reinterpret_cast<uint2*>(&hs[row][c4]) = pw;
  }
  const int lane = t & 63, w = t >> 6, l15 = lane & 15, l4 = lane >> 4;
  const f32x4 z = {0.f, 0.f, 0.f, 0.f};
  f32x4 acc[4];
#pragma unroll
  for (int jn = 0; jn < 4; ++jn) acc[jn] = z;
#pragma unroll 1
  for (int ks = 0; ks < 8; ++ks) {
    __syncthreads();                       // hs ready (ks=0) / wt safe to overwrite
    // stage W[ks*32..+32][0..256] transposed into wt[d][k]
#pragma unroll
    for (int rr = 0; rr < 8; ++rr) {
      const int flat = rr * 256 + t;
      const int k = flat >> 6, d0 = (flat & 63) * 4;
      f32x4 wv = *reinterpret_cast<const f32x4*>(W + (size_t)(ks * 32 + k) * DD + d0);
      wt[d0 + 0][k] = f2bf(wv[0]);
      wt[d0 + 1][k] = f2bf(wv[1]);
      wt[d0 + 2][k] = f2bf(wv[2]);
      wt[d0 + 3][k] = f2bf(wv[3]);
    }
    __syncthreads();
    s16x8 af = *reinterpret_cast<const s16x8*>(&hs[l15][ks * 32 + l4 * 8]);
#pragma unroll
    for (int jn = 0; jn < 4; ++jn) {
      const int dt = w * 4 + jn;
      s16x8 bf = *reinterpret_cast<const s16x8*>(&wt[dt * 16 + l15][l4 * 8]);
      acc[jn] = __builtin_amdgcn_mfma_f32_16x16x32_bf16(af, bf, acc[jn], 0, 0, 0);
    }
  }
  // epilogue: C/D 16x16: row(u_loc)=l4*4+r, col(d)=l15
#pragma unroll
  for (int jn = 0; jn < 4; ++jn) {
    const int d = w * 64 + jn * 16 + l15;
#pragma unroll
    for (int r = 0; r < 4; ++r) {
      const int ul = l4 * 4 + r;
      us hv = f2bf(acc[jn][r]);
      hWb[(size_t)(u0 + ul) * DD + d] = hv;
      lt[ul][d] = hv;
    }
  }
  __syncthreads();
  // panel write: frag (dt32, sg): pos lane*8+j = P[u=sg*16+(lane>>5)*8+j][d=dt*32+(lane&31)]
  const int sg = u0 >> 4;
#pragma unroll
  for (int cc = 0; cc < 2; ++cc) {
    const int c = t * 2 + cc;
    const int dt = c >> 6, lc = c & 63;
    const int ub = (lc >> 5) * 8;
    const int d = dt * 32 + (lc & 31);
    uint4 val;
    val.x = (uint32_t)lt[ub + 0][d] | ((uint32_t)lt[ub + 1][d] << 16);
    val.y = (uint32_t)lt[ub + 2][d] | ((uint32_t)lt[ub + 3][d] << 16);
    val.z = (uint32_t)lt[ub + 4][d] | ((uint32_t)lt[ub + 5][d] << 16);
    val.w = (uint32_t)lt[ub + 6][d] | ((uint32_t)lt[ub + 7][d] << 16);
    *reinterpret_cast<uint4*>(hWbP + ((size_t)dt * 256 + sg) * 512 + lc * 8) = val;
  }
}

// ======== kernel 1: blocks 0..511 scan A (bits, colpart, row deg -> oif/oib);
// ======== blocks 512..767 compute hW1' = feat@W1 (no oi) concurrently.
__global__ __launch_bounds__(256) void k_scanhw1(const float* __restrict__ A,
                                                 const float* __restrict__ feat,
                                                 const float* __restrict__ W1,
                                                 us* __restrict__ bitsT,
                                                 unsigned char* __restrict__ colpart,
                                                 float* __restrict__ oif,
                                                 us* __restrict__ oib,
                                                 us* __restrict__ hWb,
                                                 us* __restrict__ hWbP) {
  __shared__ __align__(16) char smem[34176];
  if (blockIdx.x >= 512) {
    hw_block(feat, W1, (blockIdx.x - 512) * 16, hWb, hWbP, smem);
    return;
  }
  us* lds16 = reinterpret_cast<us*>(smem);    // [256 wv][8 u_loc]
  const int t = threadIdx.x, b = blockIdx.x;
  const int u0 = b * 8;
  uint32_t cs[16];
#pragma unroll
  for (int k = 0; k < 16; ++k) cs[k] = 0;
#pragma unroll
  for (int rb = 0; rb < 2; ++rb) {
    f32x4 a[4][4];
#pragma unroll
    for (int r = 0; r < 4; ++r) {
      const f32x4* p = reinterpret_cast<const f32x4*>(A + (size_t)(u0 + rb * 4 + r) * NN + t * 16);
#pragma unroll
      for (int c = 0; c < 4; ++c) a[r][c] = p[c];
    }
#pragma unroll
    for (int r = 0; r < 4; ++r) {
      uint32_t m = 0;
#pragma unroll
      for (int c = 0; c < 4; ++c)
#pragma unroll
        for (int j = 0; j < 4; ++j) m |= (a[r][c][j] >= TH ? 1u : 0u) << (c * 4 + j);
      lds16[t * 8 + rb * 4 + r] = (us)m;
#pragma unroll
      for (int k = 0; k < 16; ++k) cs[k] += (m >> k) & 1u;
    }
  }
  uint4 pk;
  pk.x = cs[0]  | (cs[1]  << 8) | (cs[2]  << 16) | (cs[3]  << 24);
  pk.y = cs[4]  | (cs[5]  << 8) | (cs[6]  << 16) | (cs[7]  << 24);
  pk.z = cs[8]  | (cs[9]  << 8) | (cs[10] << 16) | (cs[11] << 24);
  pk.w = cs[12] | (cs[13] << 8) | (cs[14] << 16) | (cs[15] << 24);
  *reinterpret_cast<uint4*>(colpart + (size_t)b * 4096 + t * 16) = pk;
  __syncthreads();
  uint4 wv4 = *reinterpret_cast<const uint4*>(&lds16[t * 8]);
  *reinterpret_cast<uint4*>(bitsT + (size_t)t * 4096 + u0) = wv4;
  if (t < 64) {
    const int r = t >> 3, part = t & 7;
    uint32_t s = 0;
#pragma unroll
    for (int wv = part * 32; wv < part * 32 + 32; ++wv)
      s += (uint32_t)__popc((uint32_t)lds16[wv * 8 + r]);
    s += __shfl_down(s, 4, 8);
    s += __shfl_down(s, 2, 8);
    s += __shfl_down(s, 1, 8);
    if (part == 0) {
      float val = rsqrtf((float)(s + 1u));
      oif[u0 + r] = val;
      oib[u0 + r] = f2bf(val);
    }
  }
}

// ======== kernel: hW2' = h1@W2 (standalone, 256 blocks)
__global__ __launch_bounds__(256) void k_hw(const float* __restrict__ H,
                                            const float* __restrict__ W,
                                            us* __restrict__ hWb,
                                            us* __restrict__ hWbP) {
  __shared__ __align__(16) char smem[34176];
  hw_block(H, W, blockIdx.x * 16, hWb, hWbP, smem);
}

// ======== fused SpMM: out[v][d] = relu((sum_u bit[u][v]*oi[u]*P[u][d]
//                                        + oi[v]*P[v][d]) * ii[v] + b[d])
// Grid 256 = 64 vt x 4 dq (XCD swizzle). Block 512 = 8 waves = 4 kc x 2 dn.
// Wave: 64v (2 mi A-frags) x 32d x 1024u, 32x32x16 MFMA, oib-masked expand.
__global__ __launch_bounds__(512, 2) void k_spmm(const us* __restrict__ bitsT,
                                                 const us* __restrict__ hWbP,
                                                 const us* __restrict__ hWb,
                                                 const float* __restrict__ oif,
                                                 const us* __restrict__ oib,
                                                 const unsigned char* __restrict__ colpart,
                                                 float* __restrict__ ii_g,
                                                 const float* __restrict__ bias,
                                                 float* __restrict__ dst,
                                                 int doii) {
  __shared__ float lds[4 * 64 * 68];
  __shared__ float ii_s[64];
  const int t = threadIdx.x, bb = blockIdx.x;
  const int lane = t & 63, w = t >> 6;
  const int kc = w >> 1, dn = w & 1;
  const int xcd = bb & 7, jj = bb >> 3;
  const int vt = xcd * 8 + (jj >> 2), dq = jj & 3;
  const int V0 = vt * 64, D0 = dq * 64;

  // ---- ii: integer col-degree reduce (doii) or load cached
  if (doii) {
    uint32_t* sc = reinterpret_cast<uint32_t*>(lds);
    const int v4 = t & 15, c = t >> 4;            // v-quad, 32 chunks x 16 rows
    uint32_t s0 = 0, s1 = 0;
#pragma unroll 4
    for (int r = 0; r < 16; ++r) {
      uint32_t x = *reinterpret_cast<const uint32_t*>(colpart + (size_t)(c * 16 + r) * 4096 + V0 + v4 * 4);
      s0 += x & 0x00FF00FFu;
      s1 += (x >> 8) & 0x00FF00FFu;
    }
    sc[(c * 16 + v4) * 2] = s0;
    sc[(c * 16 + v4) * 2 + 1] = s1;
    __syncthreads();
    if (t < 64) {
      const int v4b = t >> 2, sub = t & 3;
      const int reg = sub & 1, hi = sub >> 1;
      uint32_t s = 0;
#pragma unroll
      for (int cc = 0; cc < 32; ++cc)
        s += (sc[(cc * 16 + v4b) * 2 + reg] >> (hi * 16)) & 0xFFFFu;
      float val = rsqrtf((float)(s + 1u));
      ii_s[t] = val;
      ii_g[V0 + t] = val;
    }
    __syncthreads();
  } else {
    if (t < 64) ii_s[t] = ii_g[V0 + t];
    __syncthreads();
  }

  // ---- K-loop
  const int l31 = lane & 31, l5 = lane >> 5;
  const uint32_t sh = lane & 15;
  const int wsel = (lane >> 4) & 1;
  const us* A0 = bitsT + (size_t)(vt * 4 + wsel) * 4096 + kc * 1024 + l5 * 8;
  const us* A1 = bitsT + (size_t)(vt * 4 + 2 + wsel) * 4096 + kc * 1024 + l5 * 8;
  const us* Ob = oib + kc * 1024 + l5 * 8;
  const int dt = dq * 2 + dn;
  const us* Bp = hWbP + ((size_t)dt * 256 + kc * 64) * 512 + lane * 8;

  f32x16 acc0, acc1;
#pragma unroll
  for (int q = 0; q < 16; ++q) { acc0[q] = 0.f; acc1[q] = 0.f; }

  uint4 h0a = *reinterpret_cast<const uint4*>(A0);
  uint4 h1a = *reinterpret_cast<const uint4*>(A1);
  s16x8 oa = *reinterpret_cast<const s16x8*>(Ob);
  s16x8 pa = *reinterpret_cast<const s16x8*>(Bp);
  uint4 h0b = *reinterpret_cast<const uint4*>(A0 + 16);
  uint4 h1b = *reinterpret_cast<const uint4*>(A1 + 16);
  s16x8 ob = *reinterpret_cast<const s16x8*>(Ob + 16);
  s16x8 pb = *reinterpret_cast<const s16x8*>(Bp + 512);

#define XPAND(AF, H, O)                                                        \
  {                                                                            \
    const uint32_t* ou = reinterpret_cast<const uint32_t*>(&(O));              \
    uint32_t m_;                                                               \
    m_ = (((H).x >> sh) & 0x10001u) * 0xFFFFu; AF.u[0] = ou[0] & m_;           \
    m_ = (((H).y >> sh) & 0x10001u) * 0xFFFFu; AF.u[1] = ou[1] & m_;           \
    m_ = (((H).z >> sh) & 0x10001u) * 0xFFFFu; AF.u[2] = ou[2] & m_;           \
    m_ = (((H).w >> sh) & 0x10001u) * 0xFFFFu; AF.u[3] = ou[3] & m_;           \
  }

#pragma unroll 1
  for (int it = 0; it < 32; ++it) {
    {
      union { s16x8 v; uint32_t u[4]; } af0, af1;
      XPAND(af0, h0a, oa);
      XPAND(af1, h1a, oa);
      acc0 = __builtin_amdgcn_mfma_f32_32x32x16_bf16(af0.v, pa, acc0, 0, 0, 0);
      acc1 = __builtin_amdgcn_mfma_f32_32x32x16_bf16(af1.v, pa, acc1, 0, 0, 0);
      const int sA = (it * 2 + 2) & 63;            // wraps on last iter (unused)
      h0a = *reinterpret_cast<const uint4*>(A0 + sA * 16);
      h1a = *reinterpret_cast<const uint4*>(A1 + sA * 16);
      oa = *reinterpret_cast<const s16x8*>(Ob + sA * 16);
      pa = *reinterpret_cast<const s16x8*>(Bp + (size_t)sA * 512);
    }
    {
      union { s16x8 v; uint32_t u[4]; } af0, af1;
      XPAND(af0, h0b, ob);
      XPAND(af1, h1b, ob);
      acc0 = __builtin_amdgcn_mfma_f32_32x32x16_bf16(af0.v, pb, acc0, 0, 0, 0);
      acc1 = __builtin_amdgcn_mfma_f32_32x32x16_bf16(af1.v, pb, acc1, 0, 0, 0);
      const int sB = (it * 2 + 3) & 63;
      h0b = *reinterpret_cast<const uint4*>(A0 + sB * 16);
      h1b = *reinterpret_cast<const uint4*>(A1 + sB * 16);
      ob = *reinterpret_cast<const s16x8*>(Ob + sB * 16);
      pb = *reinterpret_cast<const s16x8*>(Bp + (size_t)sB * 512);
    }
  }
#undef XPAND

  // dump: C/D 32x32: col=lane&31, row=(reg&3)+8*(reg>>2)+4*(lane>>5)
  float* buf = lds + (size_t)kc * (64 * 68);
#pragma unroll
  for (int reg = 0; reg < 16; ++reg) {
    const int row = (reg & 3) + 8 * (reg >> 2) + 4 * l5;
    buf[row * 68 + dn * 32 + l31] = acc0[reg];
    buf[(32 + row) * 68 + dn * 32 + l31] = acc1[reg];
  }
  __syncthreads();

  // epilogue: thread owns (vloc = t>>3, 8 d at (t&7)*8)
  const int vloc = t >> 3, d8 = (t & 7) * 8;
  const int v = V0 + vloc;
  const float* base = lds + vloc * 68 + d8;
  f32x4 s0v = *reinterpret_cast<const f32x4*>(base);
  f32x4 s1v = *reinterpret_cast<const f32x4*>(base + 4);
#pragma unroll
  for (int q = 1; q < 4; ++q) {
    s0v += *reinterpret_cast<const f32x4*>(base + q * (64 * 68));
    s1v += *reinterpret_cast<const f32x4*>(base + q * (64 * 68) + 4);
  }
  union { s16x8 v; us u[8]; } self;
  self.v = *reinterpret_cast<const s16x8*>(hWb + (size_t)v * DD + D0 + d8);
  const float iv = ii_s[vloc];
  const float ov = oif[v];
  const f32x4 bi0 = *reinterpret_cast<const f32x4*>(bias + D0 + d8);
  const f32x4 bi1 = *reinterpret_cast<const f32x4*>(bias + D0 + d8 + 4);
  f32x4 o0, o1;
#pragma unroll
  for (int e = 0; e < 4; ++e) {
    o0[e] = fmaxf((s0v[e] + ov * bf2f(self.u[e])) * iv + bi0[e], 0.f);
    o1[e] = fmaxf((s1v[e] + ov * bf2f(self.u[e + 4])) * iv + bi1[e], 0.f);
  }
  f32x4* po = reinterpret_cast<f32x4*>(dst + (size_t)v * DD + D0 + d8);
  po[0] = o0; po[1] = o1;
}

extern "C" void kernel_launch(void* const* d_in, const int* in_sizes, int n_in,
                              void* d_out, int out_size, void* d_ws, size_t ws_size,
                              hipStream_t stream) {
  const float* A    = (const float*)d_in[0];
  const float* feat = (const float*)d_in[1];
  const float* W1   = (const float*)d_in[2];
  const float* b1   = (const float*)d_in[3];
  const float* W2   = (const float*)d_in[4];
  const float* b2   = (const float*)d_in[5];
  float* out = (float*)d_out;
  char* ws = (char*)d_ws;

  us*            bitsT   = (us*)ws;                                   // 2 MiB
  unsigned char* colpart = (unsigned char*)(ws + (2u << 20));         // 2 MiB
  us*            hWbP    = (us*)(ws + (4u << 20));                    // 2 MiB
  us*            hWb     = (us*)(ws + (6u << 20));                    // 2 MiB
  float*         oif     = (float*)(ws + (8u << 20));                 // 16 KiB
  us*            oib     = (us*)(ws + (8u << 20) + (16u << 10));      // 8 KiB
  float*         ii_g    = (float*)(ws + (8u << 20) + (24u << 10));   // 16 KiB

  // 1: A-scan (512 blocks) + feat@W1 (256 blocks), independent halves
  k_scanhw1<<<768, 256, 0, stream>>>(A, feat, W1, bitsT, colpart, oif, oib, hWb, hWbP);
  // 2: layer-1 spmm (computes ii from colpart, caches to ii_g) -> h1
  k_spmm<<<256, 512, 0, stream>>>(bitsT, hWbP, hWb, oif, oib, colpart, ii_g, b1, out, 1);
  // 3: h1@W2
  k_hw<<<256, 256, 0, stream>>>(out, W2, hWb, hWbP);
  // 4: layer-2 spmm
  k_spmm<<<256, 512, 0, stream>>>(bitsT, hWbP, hWb, oif, oib, colpart, ii_g, b2,
                                  out + (size_t)NN * DD, 0);
}

// Round 8
// 79.966 us; speedup vs baseline: 1.0796x; 1.0796x over previous
//
#include <hip/hip_runtime.h>
#include <stdint.h>

#define NN 4096
#define DD 256
#define TH 0.04f

typedef __attribute__((ext_vector_type(4))) float f32x4;
typedef __attribute__((ext_vector_type(16))) float f32x16;
typedef __attribute__((ext_vector_type(8))) short s16x8;
typedef unsigned short us;

__device__ __forceinline__ us f2bf(float f) {
  union { float f; uint32_t u; } x; x.f = f;
  uint32_t u = x.u;
  return (us)((u + 0x7FFFu + ((u >> 16) & 1u)) >> 16);  // RNE
}
__device__ __forceinline__ float bf2f(us h) {
  union { uint32_t u; float f; } x; x.u = ((uint32_t)h) << 16;
  return x.f;
}

// ======== hw (self-staged W): P = H@W -> hWb [u][d] bf16 + 32x32 B-frag
// panels hWbP[dt(8)][sg(256)][512]. 16 u-rows/block. No oi scaling.
__device__ __forceinline__ void hw_selfstage(const float* __restrict__ H,
                                             const float* __restrict__ W,
                                             int u0,
                                             us* __restrict__ hWb,
                                             us* __restrict__ hWbP,
                                             char* smem) {
  us (*hs)[264] = reinterpret_cast<us(*)[264]>(smem);                    // 8448 B
  us (*wt)[34]  = reinterpret_cast<us(*)[34]>(smem + 16 * 264 * 2);      // 17408 B
  us (*lt)[260] = reinterpret_cast<us(*)[260]>(smem + 16 * 264 * 2 + 256 * 34 * 2); // 8320 B
  const int t = threadIdx.x;
#pragma unroll
  for (int rep = 0; rep < 4; ++rep) {
    const int flat = rep * 256 + t;
    const int row = flat >> 6, c4 = (flat & 63) * 4;
    f32x4 v = *reinterpret_cast<const f32x4*>(H + (size_t)(u0 + row) * DD + c4);
    uint2 pw;
    pw.x = (uint32_t)f2bf(v[0]) | ((uint32_t)f2bf(v[1]) << 16);
    pw.y = (uint32_t)f2bf(v[2]) | ((uint32_t)f2bf(v[3]) << 16);
    *reinterpret_cast<uint2*>(&hs[row][c4]) = pw;
  }
  const int lane = t & 63, w = t >> 6, l15 = lane & 15, l4 = lane >> 4;
  const f32x4 z = {0.f, 0.f, 0.f, 0.f};
  f32x4 acc[4];
#pragma unroll
  for (int jn = 0; jn < 4; ++jn) acc[jn] = z;
#pragma unroll 1
  for (int ks = 0; ks < 8; ++ks) {
    __syncthreads();
#pragma unroll
    for (int rr = 0; rr < 8; ++rr) {
      const int flat = rr * 256 + t;
      const int k = flat >> 6, d0 = (flat & 63) * 4;
      f32x4 wv = *reinterpret_cast<const f32x4*>(W + (size_t)(ks * 32 + k) * DD + d0);
      wt[d0 + 0][k] = f2bf(wv[0]);
      wt[d0 + 1][k] = f2bf(wv[1]);
      wt[d0 + 2][k] = f2bf(wv[2]);
      wt[d0 + 3][k] = f2bf(wv[3]);
    }
    __syncthreads();
    s16x8 af = *reinterpret_cast<const s16x8*>(&hs[l15][ks * 32 + l4 * 8]);
#pragma unroll
    for (int jn = 0; jn < 4; ++jn) {
      const int dt = w * 4 + jn;
      s16x8 bf = *reinterpret_cast<const s16x8*>(&wt[dt * 16 + l15][l4 * 8]);
      acc[jn] = __builtin_amdgcn_mfma_f32_16x16x32_bf16(af, bf, acc[jn], 0, 0, 0);
    }
  }
#pragma unroll
  for (int jn = 0; jn < 4; ++jn) {
    const int d = w * 64 + jn * 16 + l15;
#pragma unroll
    for (int r = 0; r < 4; ++r) {
      const int ul = l4 * 4 + r;              // C/D 16x16: row=l4*4+r, col=l15
      us hv = f2bf(acc[jn][r]);
      hWb[(size_t)(u0 + ul) * DD + d] = hv;
      lt[ul][d] = hv;
    }
  }
  __syncthreads();
  const int sg = u0 >> 4;
#pragma unroll
  for (int cc = 0; cc < 2; ++cc) {
    const int c = t * 2 + cc;
    const int dt = c >> 6, lc = c & 63;
    const int ub = (lc >> 5) * 8;
    const int d = dt * 32 + (lc & 31);
    uint4 val;
    val.x = (uint32_t)lt[ub + 0][d] | ((uint32_t)lt[ub + 1][d] << 16);
    val.y = (uint32_t)lt[ub + 2][d] | ((uint32_t)lt[ub + 3][d] << 16);
    val.z = (uint32_t)lt[ub + 4][d] | ((uint32_t)lt[ub + 5][d] << 16);
    val.w = (uint32_t)lt[ub + 6][d] | ((uint32_t)lt[ub + 7][d] << 16);
    *reinterpret_cast<uint4*>(hWbP + ((size_t)dt * 256 + sg) * 512 + lc * 8) = val;
  }
}

// ======== launch 1: blocks 0..511 scan A (bitsT, colpart, oif/oib; blocks
// 0..15 also emit W2 16x16-frag panels); blocks 512..767 hW1' = feat@W1.
__global__ __launch_bounds__(256) void k_scanhw1(const float* __restrict__ A,
                                                 const float* __restrict__ feat,
                                                 const float* __restrict__ W1,
                                                 const float* __restrict__ W2,
                                                 us* __restrict__ bitsT,
                                                 unsigned char* __restrict__ colpart,
                                                 float* __restrict__ oif,
                                                 us* __restrict__ oib,
                                                 us* __restrict__ hWb,
                                                 us* __restrict__ hWbP,
                                                 us* __restrict__ W2TbP) {
  __shared__ __align__(16) char smem[34176];
  if (blockIdx.x >= 512) {
    hw_selfstage(feat, W1, (blockIdx.x - 512) * 16, hWb, hWbP, smem);
    return;
  }
  us* lds16 = reinterpret_cast<us*>(smem);    // [256 wv][8 u_loc]
  const int t = threadIdx.x, b = blockIdx.x;
  const int u0 = b * 8;
  uint32_t cs[16];
#pragma unroll
  for (int k = 0; k < 16; ++k) cs[k] = 0;
#pragma unroll
  for (int rb = 0; rb < 2; ++rb) {
    f32x4 a[4][4];
#pragma unroll
    for (int r = 0; r < 4; ++r) {
      const f32x4* p = reinterpret_cast<const f32x4*>(A + (size_t)(u0 + rb * 4 + r) * NN + t * 16);
#pragma unroll
      for (int c = 0; c < 4; ++c) a[r][c] = p[c];
    }
#pragma unroll
    for (int r = 0; r < 4; ++r) {
      uint32_t m = 0;
#pragma unroll
      for (int c = 0; c < 4; ++c)
#pragma unroll
        for (int j = 0; j < 4; ++j) m |= (a[r][c][j] >= TH ? 1u : 0u) << (c * 4 + j);
      lds16[t * 8 + rb * 4 + r] = (us)m;
#pragma unroll
      for (int k = 0; k < 16; ++k) cs[k] += (m >> k) & 1u;
    }
  }
  uint4 pk;
  pk.x = cs[0]  | (cs[1]  << 8) | (cs[2]  << 16) | (cs[3]  << 24);
  pk.y = cs[4]  | (cs[5]  << 8) | (cs[6]  << 16) | (cs[7]  << 24);
  pk.z = cs[8]  | (cs[9]  << 8) | (cs[10] << 16) | (cs[11] << 24);
  pk.w = cs[12] | (cs[13] << 8) | (cs[14] << 16) | (cs[15] << 24);
  *reinterpret_cast<uint4*>(colpart + (size_t)b * 4096 + t * 16) = pk;
  __syncthreads();
  uint4 wv4 = *reinterpret_cast<const uint4*>(&lds16[t * 8]);
  *reinterpret_cast<uint4*>(bitsT + (size_t)t * 4096 + u0) = wv4;
  if (t < 64) {
    const int r = t >> 3, part = t & 7;
    uint32_t s = 0;
#pragma unroll
    for (int wv = part * 32; wv < part * 32 + 32; ++wv)
      s += (uint32_t)__popc((uint32_t)lds16[wv * 8 + r]);
    s += __shfl_down(s, 4, 8);
    s += __shfl_down(s, 2, 8);
    s += __shfl_down(s, 1, 8);
    if (part == 0) {
      float val = rsqrtf((float)(s + 1u));
      oif[u0 + r] = val;
      oib[u0 + r] = f2bf(val);
    }
  }
  // W2 -> 16x16 B-frag panels (blocks 0..15): frag (dt16,ks32): pos lane*8+j
  //   = W2[k = ks*32 + (lane>>4)*8 + j][d = dt*16 + (lane&15)]
  if (b < 16) {
    const int base = b * 4096 + t * 16;
#pragma unroll
    for (int e = 0; e < 16; ++e) {
      const int idx = base + e;
      const int frag = idx >> 9, pos = idx & 511;
      const int lc = pos >> 3, j = pos & 7;
      const int dt = frag >> 3, ks = frag & 7;
      const int k = ks * 32 + (lc >> 4) * 8 + j;
      const int d = dt * 16 + (lc & 15);
      W2TbP[idx] = f2bf(W2[k * 256 + d]);
    }
  }
}

// ======== hW2' = h1@W2 via pre-built W2 panels. 256 blocks, 16 rows each.
__global__ __launch_bounds__(256) void k_hw2(const float* __restrict__ H,
                                             const us* __restrict__ WP,
                                             us* __restrict__ hWb,
                                             us* __restrict__ hWbP) {
  __shared__ us hs[16][264];
  __shared__ us lt[16][260];
  const int t = threadIdx.x;
  const int u0 = blockIdx.x * 16;
#pragma unroll
  for (int rep = 0; rep < 4; ++rep) {
    const int flat = rep * 256 + t;
    const int row = flat >> 6, c4 = (flat & 63) * 4;
    f32x4 v = *reinterpret_cast<const f32x4*>(H + (size_t)(u0 + row) * DD + c4);
    uint2 pw;
    pw.x = (uint32_t)f2bf(v[0]) | ((uint32_t)f2bf(v[1]) << 16);
    pw.y = (uint32_t)f2bf(v[2]) | ((uint32_t)f2bf(v[3]) << 16);
    *reinterpret_cast<uint2*>(&hs[row][c4]) = pw;
  }
  __syncthreads();
  const int lane = t & 63, w = t >> 6, l15 = lane & 15, l4 = lane >> 4;
  const f32x4 z = {0.f, 0.f, 0.f, 0.f};
  f32x4 acc[4];
#pragma unroll
  for (int jn = 0; jn < 4; ++jn) acc[jn] = z;
#pragma unroll
  for (int ks = 0; ks < 8; ++ks) {
    s16x8 af = *reinterpret_cast<const s16x8*>(&hs[l15][ks * 32 + l4 * 8]);
#pragma unroll
    for (int jn = 0; jn < 4; ++jn) {
      const int dt = w * 4 + jn;
      s16x8 bf = *reinterpret_cast<const s16x8*>(WP + ((size_t)dt * 8 + ks) * 512 + lane * 8);
      acc[jn] = __builtin_amdgcn_mfma_f32_16x16x32_bf16(af, bf, acc[jn], 0, 0, 0);
    }
  }
#pragma unroll
  for (int jn = 0; jn < 4; ++jn) {
    const int d = w * 64 + jn * 16 + l15;
#pragma unroll
    for (int r = 0; r < 4; ++r) {
      const int ul = l4 * 4 + r;
      us hv = f2bf(acc[jn][r]);
      hWb[(size_t)(u0 + ul) * DD + d] = hv;
      lt[ul][d] = hv;
    }
  }
  __syncthreads();
  const int sg = u0 >> 4;
#pragma unroll
  for (int cc = 0; cc < 2; ++cc) {
    const int c = t * 2 + cc;
    const int dt = c >> 6, lc = c & 63;
    const int ub = (lc >> 5) * 8;
    const int d = dt * 32 + (lc & 31);
    uint4 val;
    val.x = (uint32_t)lt[ub + 0][d] | ((uint32_t)lt[ub + 1][d] << 16);
    val.y = (uint32_t)lt[ub + 2][d] | ((uint32_t)lt[ub + 3][d] << 16);
    val.z = (uint32_t)lt[ub + 4][d] | ((uint32_t)lt[ub + 5][d] << 16);
    val.w = (uint32_t)lt[ub + 6][d] | ((uint32_t)lt[ub + 7][d] << 16);
    *reinterpret_cast<uint4*>(hWbP + ((size_t)dt * 256 + sg) * 512 + lc * 8) = val;
  }
}

// ======== fused SpMM: out[v][d] = relu((sum_u bit[u][v]*oib[u]*P[u][d]
//                                        + oif[v]*P[v][d]) * ii[v] + b[d])
// Grid 256 = 64vt x 4dq XCD-swizzled; block 512 = 8 waves = 4kc x 2mi.
// Wave: 32v (1 A-expand) x 64d (2 B-frag MFMAs) x K1024. Depth-4 prefetch.
__global__ __launch_bounds__(512, 2) void k_spmm(const us* __restrict__ bitsT,
                                                 const us* __restrict__ hWbP,
                                                 const us* __restrict__ hWb,
                                                 const float* __restrict__ oif,
                                                 const us* __restrict__ oib,
                                                 const unsigned char* __restrict__ colpart,
                                                 float* __restrict__ ii_g,
                                                 const float* __restrict__ bias,
                                                 float* __restrict__ dst,
                                                 int doii) {
  __shared__ float lds[4 * 64 * 68];
  __shared__ float ii_s[64];
  const int t = threadIdx.x, bb = blockIdx.x;
  const int lane = t & 63, w = t >> 6;
  const int mi = w & 1, kc = w >> 1;
  const int xcd = bb & 7, jj = bb >> 3;
  const int vt = xcd * 8 + (jj >> 2), dq = jj & 3;
  const int V0 = vt * 64, D0 = dq * 64;

  if (doii) {
    uint32_t* sc = reinterpret_cast<uint32_t*>(lds);
    const int v4 = t & 15, c = t >> 4;
    uint32_t s0 = 0, s1 = 0;
#pragma unroll 4
    for (int r = 0; r < 16; ++r) {
      uint32_t x = *reinterpret_cast<const uint32_t*>(colpart + (size_t)(c * 16 + r) * 4096 + V0 + v4 * 4);
      s0 += x & 0x00FF00FFu;
      s1 += (x >> 8) & 0x00FF00FFu;
    }
    sc[(c * 16 + v4) * 2] = s0;
    sc[(c * 16 + v4) * 2 + 1] = s1;
    __syncthreads();
    if (t < 64) {
      const int v4b = t >> 2, sub = t & 3;
      const int reg = sub & 1, hi = sub >> 1;
      uint32_t s = 0;
#pragma unroll
      for (int cc = 0; cc < 32; ++cc)
        s += (sc[(cc * 16 + v4b) * 2 + reg] >> (hi * 16)) & 0xFFFFu;
      float val = rsqrtf((float)(s + 1u));
      ii_s[t] = val;
      ii_g[V0 + t] = val;
    }
    __syncthreads();
  } else {
    if (t < 64) ii_s[t] = ii_g[V0 + t];
    __syncthreads();
  }

  const int l31 = lane & 31, l5 = lane >> 5;
  const uint32_t sh = lane & 15;
  const int wvl = vt * 4 + mi * 2 + ((lane >> 4) & 1);
  const us* Ab = bitsT + (size_t)wvl * 4096 + kc * 1024 + l5 * 8;
  const us* Ob = oib + kc * 1024 + l5 * 8;
  const us* Bp0 = hWbP + ((size_t)(dq * 2 + 0) * 256 + kc * 64) * 512 + lane * 8;
  const us* Bp1 = hWbP + ((size_t)(dq * 2 + 1) * 256 + kc * 64) * 512 + lane * 8;

  f32x16 acc0, acc1;
#pragma unroll
  for (int q = 0; q < 16; ++q) { acc0[q] = 0.f; acc1[q] = 0.f; }

  uint4 h[4]; s16x8 o[4], p0[4], p1[4];
#pragma unroll
  for (int sl = 0; sl < 4; ++sl) {
    h[sl]  = *reinterpret_cast<const uint4*>(Ab + sl * 16);
    o[sl]  = *reinterpret_cast<const s16x8*>(Ob + sl * 16);
    p0[sl] = *reinterpret_cast<const s16x8*>(Bp0 + (size_t)sl * 512);
    p1[sl] = *reinterpret_cast<const s16x8*>(Bp1 + (size_t)sl * 512);
  }

#pragma unroll 1
  for (int it = 0; it < 16; ++it) {
#pragma unroll
    for (int sl = 0; sl < 4; ++sl) {
      union { s16x8 v; uint32_t u[4]; } af;
      const uint32_t* ou = reinterpret_cast<const uint32_t*>(&o[sl]);
      uint32_t m;
      m = ((h[sl].x >> sh) & 0x10001u) * 0xFFFFu; af.u[0] = ou[0] & m;
      m = ((h[sl].y >> sh) & 0x10001u) * 0xFFFFu; af.u[1] = ou[1] & m;
      m = ((h[sl].z >> sh) & 0x10001u) * 0xFFFFu; af.u[2] = ou[2] & m;
      m = ((h[sl].w >> sh) & 0x10001u) * 0xFFFFu; af.u[3] = ou[3] & m;
      acc0 = __builtin_amdgcn_mfma_f32_32x32x16_bf16(af.v, p0[sl], acc0, 0, 0, 0);
      acc1 = __builtin_amdgcn_mfma_f32_32x32x16_bf16(af.v, p1[sl], acc1, 0, 0, 0);
      const int ns = (it * 4 + sl + 4) & 63;       // wraps at tail (unused)
      h[sl]  = *reinterpret_cast<const uint4*>(Ab + ns * 16);
      o[sl]  = *reinterpret_cast<const s16x8*>(Ob + ns * 16);
      p0[sl] = *reinterpret_cast<const s16x8*>(Bp0 + (size_t)ns * 512);
      p1[sl] = *reinterpret_cast<const s16x8*>(Bp1 + (size_t)ns * 512);
    }
  }

  // dump: C/D 32x32: col=lane&31, row=(reg&3)+8*(reg>>2)+4*(lane>>5)
  float* buf = lds + (size_t)kc * (64 * 68);
#pragma unroll
  for (int reg = 0; reg < 16; ++reg) {
    const int row = (reg & 3) + 8 * (reg >> 2) + 4 * l5;
    buf[(mi * 32 + row) * 68 + l31] = acc0[reg];
    buf[(mi * 32 + row) * 68 + 32 + l31] = acc1[reg];
  }
  __syncthreads();

  const int vloc = t >> 3, d8 = (t & 7) * 8;
  const int v = V0 + vloc;
  const float* base = lds + vloc * 68 + d8;
  f32x4 s0v = *reinterpret_cast<const f32x4*>(base);
  f32x4 s1v = *reinterpret_cast<const f32x4*>(base + 4);
#pragma unroll
  for (int q = 1; q < 4; ++q) {
    s0v += *reinterpret_cast<const f32x4*>(base + q * (64 * 68));
    s1v += *reinterpret_cast<const f32x4*>(base + q * (64 * 68) + 4);
  }
  union { s16x8 v; us u[8]; } self;
  self.v = *reinterpret_cast<const s16x8*>(hWb + (size_t)v * DD + D0 + d8);
  const float iv = ii_s[vloc];
  const float ov = oif[v];
  const f32x4 bi0 = *reinterpret_cast<const f32x4*>(bias + D0 + d8);
  const f32x4 bi1 = *reinterpret_cast<const f32x4*>(bias + D0 + d8 + 4);
  f32x4 o0, o1;
#pragma unroll
  for (int e = 0; e < 4; ++e) {
    o0[e] = fmaxf((s0v[e] + ov * bf2f(self.u[e])) * iv + bi0[e], 0.f);
    o1[e] = fmaxf((s1v[e] + ov * bf2f(self.u[e + 4])) * iv + bi1[e], 0.f);
  }
  f32x4* po = reinterpret_cast<f32x4*>(dst + (size_t)v * DD + D0 + d8);
  po[0] = o0; po[1] = o1;
}

extern "C" void kernel_launch(void* const* d_in, const int* in_sizes, int n_in,
                              void* d_out, int out_size, void* d_ws, size_t ws_size,
                              hipStream_t stream) {
  const float* A    = (const float*)d_in[0];
  const float* feat = (const float*)d_in[1];
  const float* W1   = (const float*)d_in[2];
  const float* b1   = (const float*)d_in[3];
  const float* W2   = (const float*)d_in[4];
  const float* b2   = (const float*)d_in[5];
  float* out = (float*)d_out;
  char* ws = (char*)d_ws;

  us*            bitsT   = (us*)ws;                                   // 2 MiB
  unsigned char* colpart = (unsigned char*)(ws + (2u << 20));         // 2 MiB
  us*            hWbP    = (us*)(ws + (4u << 20));                    // 2 MiB
  us*            hWb     = (us*)(ws + (6u << 20));                    // 2 MiB
  us*            W2TbP   = (us*)(ws + (8u << 20));                    // 128 KiB
  float*         oif     = (float*)(ws + (8u << 20) + (1u << 17));    // 16 KiB
  us*            oib     = (us*)(ws + (8u << 20) + (1u << 17) + (16u << 10));
  float*         ii_g    = (float*)(ws + (8u << 20) + (1u << 17) + (24u << 10));

  // 1: A-scan (blocks 0-511, also W2 panels) + feat@W1 (blocks 512-767)
  k_scanhw1<<<768, 256, 0, stream>>>(A, feat, W1, W2, bitsT, colpart, oif, oib,
                                     hWb, hWbP, W2TbP);
  // 2: layer-1 spmm (computes ii, caches to ii_g) -> h1
  k_spmm<<<256, 512, 0, stream>>>(bitsT, hWbP, hWb, oif, oib, colpart, ii_g, b1, out, 1);
  // 3: h1@W2 via W2 panels
  k_hw2<<<256, 256, 0, stream>>>(out, W2TbP, hWb, hWbP);
  // 4: layer-2 spmm
  k_spmm<<<256, 512, 0, stream>>>(bitsT, hWbP, hWb, oif, oib, colpart, ii_g, b2,
                                  out + (size_t)NN * DD, 0);
}